// Round 14
// baseline (18185.463 us; speedup 1.0000x reference)
//
#include <hip/hip_runtime.h>
#include <math.h>

#define ESN_B 16
#define ESN_T 2048
#define ESN_R 1024
#define ESN_IN 64
#define NBR (ESN_B * ESN_R)

// ---- workspace layout (float offsets) ----
#define OFF_WT_HH0 0                               // [1024][1024]  W_hh0^T
#define OFF_WT_IN1 (1024 * 1024)                   // [1024][1024]  W_in1^T
#define OFF_WT_HH1 (2 * 1024 * 1024)               // [1024][1024]  W_hh1^T
#define OFF_WT_IN0 (3 * 1024 * 1024)               // [1024][64]    W_in0^T
#define OFF_RT     (OFF_WT_IN0 + 1024 * 64)        // [64][2048]    readout^T
#define OFF_S0G    (OFF_RT + 64 * 2048)            // [2][16][1024] s0 double buffer
#define OFF_S1G    (OFF_S0G + 2 * NBR)             // [2][16][1024] s1 double buffer
#define OFF_FLAGS  (OFF_S1G + 2 * NBR)             // [4][64] u32 per-block flags

typedef float vfloat4 __attribute__((__vector_size__(16)));

// ---------------- transpose: dst[c][r] = src[r][c] ----------------
__global__ void __launch_bounds__(256) transpose_k(const float* __restrict__ src,
                                                   float* __restrict__ dst,
                                                   int rows, int cols) {
  __shared__ float tile[32][33];
  int bx = blockIdx.x * 32, by = blockIdx.y * 32;
  int tx = threadIdx.x, ty = threadIdx.y;  // 32 x 8
  #pragma unroll
  for (int i = ty; i < 32; i += 8) {
    int r = by + i, c = bx + tx;
    if (r < rows && c < cols) tile[i][tx] = src[(size_t)r * cols + c];
  }
  __syncthreads();
  #pragma unroll
  for (int i = ty; i < 32; i += 8) {
    int c = bx + i, r = by + tx;
    if (c < cols && r < rows) dst[(size_t)c * rows + r] = tile[tx][i];
  }
}

// ---------------- helpers ----------------
__device__ __forceinline__ float fast_tanh(float v) {
  float a = fabsf(v);
  float e = __expf(-2.0f * a);
  float t = __fdividef(1.0f - e, 1.0f + e);
  return copysignf(t, v);
}

__device__ __forceinline__ float dot4(float4 a, float4 b, float acc) {
  acc = fmaf(a.x, b.x, acc);
  acc = fmaf(a.y, b.y, acc);
  acc = fmaf(a.z, b.z, acc);
  acc = fmaf(a.w, b.w, acc);
  return acc;
}

__device__ __forceinline__ float wave_red64(float v) {
  #pragma unroll
  for (int off = 32; off > 0; off >>= 1) v += __shfl_xor(v, off, 64);
  return v;
}

// device-scope (LLC-coherent) memory ops: bypass L1/L2, no cache invalidates
__device__ __forceinline__ void llc_store_f32x4(float* p, float4 v) {
  vfloat4 vv = {v.x, v.y, v.z, v.w};
  asm volatile("global_store_dwordx4 %0, %1, off sc1" :: "v"(p), "v"(vv) : "memory");
}
__device__ __forceinline__ void llc_store_u32(unsigned* p, unsigned v) {
  asm volatile("global_store_dword %0, %1, off sc1" :: "v"(p), "v"(v) : "memory");
}
__device__ __forceinline__ unsigned llc_load_u32(const unsigned* p) {
  unsigned f;
  asm volatile("global_load_dword %0, %1, off sc1\n\ts_waitcnt vmcnt(0)"
               : "=v"(f) : "v"(p) : "memory");
  return f;
}
__device__ __forceinline__ void vmcnt0() {
  asm volatile("s_waitcnt vmcnt(0)" ::: "memory");
}
// raw barriers: do NOT drain vmcnt (unlike __syncthreads)
__device__ __forceinline__ void barrier_only() {
  asm volatile("" ::: "memory");
  __builtin_amdgcn_s_barrier();
  asm volatile("" ::: "memory");
}
__device__ __forceinline__ void barrier_lgkm() {
  asm volatile("s_waitcnt lgkmcnt(0)" ::: "memory");
  __builtin_amdgcn_s_barrier();
  asm volatile("" ::: "memory");
}

// ---------------- persistent fused scan ----------------
// 4 groups x 64 blocks x 1024 threads (16 waves; 88KB LDS -> 1 block/CU ->
// 4 waves/SIMD: doubles latency hiding vs r13's 2/SIMD, targeting the
// ~2.6us/round exposed-latency bucket). Wave owns 1 col x 4 batches
// (48 weight VGPRs; <=128 cap for 16-wave residency). Waves 12-15 also do
// readout (1 task/wave). Protocol identical to r13: sc1 exchange,
// per-block flags, 4 raw barriers, round loop unrolled x2 (compile-time slot).
__global__ void __launch_bounds__(1024, 1) esn_scan_kernel(
    const float* __restrict__ x,
    const float* __restrict__ b0,
    const float* __restrict__ b1,
    float* __restrict__ wsf,
    float* __restrict__ out) {
  __shared__ float s0l[2][4][1024];  // s0 LDS ring: slot r&1 = s0(r-1)
  __shared__ float s1l[4][1024];     // s1(r-2)
  __shared__ __align__(16) float res[2][4][16];  // [layer][batch][16 cols]
  extern __shared__ float dyn_pad[]; // 40KB occupancy limiter (never touched)
  if (blockIdx.x == 0x7fffffffu) dyn_pad[0] = 1.0f;  // defeat DCE, never runs

  const float* wtHH0 = wsf + OFF_WT_HH0;
  const float* wtIN1 = wsf + OFF_WT_IN1;
  const float* wtHH1 = wsf + OFF_WT_HH1;
  const float* wtIN0 = wsf + OFF_WT_IN0;
  const float* rt    = wsf + OFF_RT;
  float* s0g = wsf + OFF_S0G;
  float* s1g = wsf + OFF_S1G;
  unsigned* flags = (unsigned*)(wsf + OFF_FLAGS);

  const int tid = threadIdx.x;
  const int l = tid & 63;
  const int w = tid >> 6;            // wave 0..15
  const int bid = blockIdx.x;
  const int g = bid >> 6;            // group 0..3
  const int bg = bid & 63;           // block in group
  const int batch0 = g * 4;
  const int c0 = bg * 16 + w;        // wave's column (1 col/wave)
  const bool doRO = (w >= 12);       // waves 12..15: readout (1 task each)
  const int rbl = w - 12;            // readout local batch
  const int rb = batch0 + rbl;       // readout batch
  const int roc = bg;                // readout out-col
  unsigned* gflags = flags + g * 64; // [64 blocks]

  // ---- persistent per-lane weights (1 col; k = q*256 + l*4 + j) ----
  float4 wA_0, wA_1, wA_2, wA_3;     // W_hh0^T col c0
  float4 wB_0, wB_1, wB_2, wB_3;     // W_in1^T col c0
  float4 wC_0, wC_1, wC_2, wC_3;     // W_hh1^T col c0
  float4 rd0, rd1, rd2, rd3, rd4, rd5, rd6, rd7;
  {
    const float* pA = wtHH0 + (size_t)c0 * ESN_R + l * 4;
    const float* pB = wtIN1 + (size_t)c0 * ESN_R + l * 4;
    const float* pC = wtHH1 + (size_t)c0 * ESN_R + l * 4;
    wA_0 = *(const float4*)(pA);       wA_1 = *(const float4*)(pA + 256);
    wA_2 = *(const float4*)(pA + 512); wA_3 = *(const float4*)(pA + 768);
    wB_0 = *(const float4*)(pB);       wB_1 = *(const float4*)(pB + 256);
    wB_2 = *(const float4*)(pB + 512); wB_3 = *(const float4*)(pB + 768);
    wC_0 = *(const float4*)(pC);       wC_1 = *(const float4*)(pC + 256);
    wC_2 = *(const float4*)(pC + 512); wC_3 = *(const float4*)(pC + 768);
  }
  rd0 = rd1 = rd2 = rd3 = rd4 = rd5 = rd6 = rd7 = make_float4(0.f, 0.f, 0.f, 0.f);
  if (doRO) {
    const float* pr = rt + (size_t)roc * 2048 + l * 4;
    rd0 = *(const float4*)(pr);        rd1 = *(const float4*)(pr + 256);
    rd2 = *(const float4*)(pr + 512);  rd3 = *(const float4*)(pr + 768);
    rd4 = *(const float4*)(pr + 1024); rd5 = *(const float4*)(pr + 1280);
    rd6 = *(const float4*)(pr + 1536); rd7 = *(const float4*)(pr + 1792);
  }
  const float wI = wtIN0[(size_t)c0 * ESN_IN + l];
  const float b0sel = b0[c0];
  const float b1sel = b1[c0];

  // ---- hoisted pointers (slot-specific, compile-time selected below) ----
  const float* sA0 = s0g + 0 * NBR + batch0 * ESN_R + tid * 4;  // s0 slot0
  const float* sA1 = s0g + 1 * NBR + batch0 * ESN_R + tid * 4;  // s0 slot1
  const float* sB0 = s1g + 0 * NBR + batch0 * ESN_R + tid * 4;
  const float* sB1 = s1g + 1 * NBR + batch0 * ESN_R + tid * 4;
  const int soff = (l >> 2) * ESN_R + (l & 3) * 4;              // lanes 0..15
  float* st0A = s0g + 0 * NBR + batch0 * ESN_R + bg * 16 + soff;
  float* st0B = s0g + 1 * NBR + batch0 * ESN_R + bg * 16 + soff;
  float* st1A = s1g + 0 * NBR + batch0 * ESN_R + bg * 16 + soff;
  float* st1B = s1g + 1 * NBR + batch0 * ESN_R + bg * 16 + soff;
  const float* xbase = x + (size_t)batch0 * ESN_T * ESN_IN + l;

  // One round with compile-time SLOTC (0 or 1). oslot = 1-SLOTC.
#define ESN_ROUND(SLOTC, rr)                                                   \
  {                                                                            \
    const bool doL0 = ((rr) < ESN_T);                                          \
    const bool doL1 = ((rr) >= 1 && (rr) <= ESN_T);                            \
    float xv0 = 0.f, xv1 = 0.f, xv2 = 0.f, xv3 = 0.f;                          \
    if (doL0) {                                                                \
      const float* xp = xbase + (size_t)(rr) * ESN_IN;                         \
      xv0 = xp[0 * ESN_T * ESN_IN];                                            \
      xv1 = xp[1 * ESN_T * ESN_IN];                                            \
      xv2 = xp[2 * ESN_T * ESN_IN];                                            \
      xv3 = xp[3 * ESN_T * ESN_IN];                                            \
    }                                                                          \
    vmcnt0();                                                                  \
    if ((rr) > 0) {                                                            \
      if (w == 0) {                                                            \
        while (!__all(llc_load_u32(&gflags[l]) >= (unsigned)(rr))) {}          \
      }                                                                        \
      barrier_only(); /* syncA */                                              \
    }                                                                          \
    const float* p0 = SLOTC ? sA0 : sA1; /* stage reads oslot buffers */       \
    const float* p1 = SLOTC ? sB0 : sB1;                                       \
    float4 t0, u0;                                                             \
    asm volatile(                                                              \
        "global_load_dwordx4 %0, %2, off sc1\n\t"                              \
        "global_load_dwordx4 %1, %3, off sc1\n\t"                              \
        "s_waitcnt vmcnt(1)"                                                   \
        : "=&v"(t0), "=&v"(u0)                                                 \
        : "v"(p0), "v"(p1)                                                     \
        : "memory");                                                           \
    *(float4*)(&s0l[SLOTC][0][0] + tid * 4) = t0;                              \
    barrier_lgkm(); /* syncB: s0l ready; s1 load in flight */                  \
    if (doL0) {                                                                \
      _Pragma("unroll")                                                        \
      for (int bb = 0; bb < 4; ++bb) {                                         \
        const float* hp = &s0l[SLOTC][bb][l * 4];                              \
        float4 h0x = *(const float4*)(hp);                                     \
        float4 h1x = *(const float4*)(hp + 256);                               \
        float4 h2x = *(const float4*)(hp + 512);                               \
        float4 h3x = *(const float4*)(hp + 768);                               \
        float xb = (bb == 0) ? xv0 : (bb == 1) ? xv1 : (bb == 2) ? xv2 : xv3;  \
        float a0 = xb * wI;                                                    \
        a0 = dot4(wA_0, h0x, a0); a0 = dot4(wA_1, h1x, a0);                    \
        a0 = dot4(wA_2, h2x, a0); a0 = dot4(wA_3, h3x, a0);                    \
        float C = wave_red64(a0);                                              \
        if (l == 0) {                                                          \
          float prev = s0l[SLOTC][bb][c0];                                     \
          res[0][bb][w] = 0.5f * prev + 0.5f * fast_tanh(C + b0sel);           \
        }                                                                      \
      }                                                                        \
    }                                                                          \
    vmcnt0();                                                                  \
    *(float4*)(&s1l[0][0] + tid * 4) = u0;                                     \
    barrier_lgkm(); /* syncC: s1l + res[0] ready */                            \
    if (w == 0 && l < 16 && doL0) {                                            \
      float4 v0 = *(const float4*)&res[0][l >> 2][(l & 3) * 4];                \
      llc_store_f32x4(SLOTC ? st0B : st0A, v0);                                \
    }                                                                          \
    if (doL1) {                                                                \
      _Pragma("unroll")                                                        \
      for (int bb = 0; bb < 4; ++bb) {                                         \
        const float* hp = &s0l[SLOTC][bb][l * 4];                              \
        float4 h0x = *(const float4*)(hp);                                     \
        float4 h1x = *(const float4*)(hp + 256);                               \
        float4 h2x = *(const float4*)(hp + 512);                               \
        float4 h3x = *(const float4*)(hp + 768);                               \
        const float* gp = &s1l[bb][l * 4];                                     \
        float4 g0x = *(const float4*)(gp);                                     \
        float4 g1x = *(const float4*)(gp + 256);                               \
        float4 g2x = *(const float4*)(gp + 512);                               \
        float4 g3x = *(const float4*)(gp + 768);                               \
        float a0 = 0.f;                                                        \
        a0 = dot4(wB_0, h0x, a0); a0 = dot4(wB_1, h1x, a0);                    \
        a0 = dot4(wB_2, h2x, a0); a0 = dot4(wB_3, h3x, a0);                    \
        a0 = dot4(wC_0, g0x, a0); a0 = dot4(wC_1, g1x, a0);                    \
        a0 = dot4(wC_2, g2x, a0); a0 = dot4(wC_3, g3x, a0);                    \
        float C = wave_red64(a0);                                              \
        if (l == 0) {                                                          \
          float prev = s1l[bb][c0];                                            \
          res[1][bb][w] = 0.5f * prev + 0.5f * fast_tanh(C + b1sel);           \
        }                                                                      \
      }                                                                        \
    }                                                                          \
    barrier_lgkm(); /* syncD: res[1] ready */                                  \
    if (w == 0) {                                                              \
      if (l < 16 && doL1) {                                                    \
        float4 v1 = *(const float4*)&res[1][l >> 2][(l & 3) * 4];              \
        llc_store_f32x4(SLOTC ? st1B : st1A, v1);                              \
      }                                                                        \
      vmcnt0();                                                                \
      if (l == 0) llc_store_u32(&gflags[bg], (unsigned)((rr) + 1));            \
    }                                                                          \
    if ((rr) >= 2 && doRO) {                                                   \
      const float* sp = &s0l[1 - SLOTC][rbl][l * 4];                           \
      const float* tp = &s1l[rbl][l * 4];                                      \
      float a = 0.f;                                                           \
      a = dot4(rd0, *(const float4*)(sp), a);                                  \
      a = dot4(rd1, *(const float4*)(sp + 256), a);                            \
      a = dot4(rd2, *(const float4*)(sp + 512), a);                            \
      a = dot4(rd3, *(const float4*)(sp + 768), a);                            \
      a = dot4(rd4, *(const float4*)(tp), a);                                  \
      a = dot4(rd5, *(const float4*)(tp + 256), a);                            \
      a = dot4(rd6, *(const float4*)(tp + 512), a);                            \
      a = dot4(rd7, *(const float4*)(tp + 768), a);                            \
      a = wave_red64(a);                                                       \
      if (l == 0) out[((size_t)rb * ESN_T + ((rr) - 2)) * ESN_IN + roc] = a;   \
    }                                                                          \
  }

  // 2050 rounds = 1025 unrolled pairs; slot alternates 0,1 at compile time
  for (int rp = 0; rp < (ESN_T + 2) / 2; ++rp) {
    const int r0 = rp * 2;
    ESN_ROUND(0, r0)
    ESN_ROUND(1, r0 + 1)
  }
#undef ESN_ROUND
}

// ---------------- host launch ----------------
extern "C" void kernel_launch(void* const* d_in, const int* in_sizes, int n_in,
                              void* d_out, int out_size, void* d_ws, size_t ws_size,
                              hipStream_t stream) {
  (void)in_sizes; (void)n_in; (void)out_size; (void)ws_size;
  const float* x     = (const float*)d_in[0];
  const float* w_in0 = (const float*)d_in[1];
  const float* w_hh0 = (const float*)d_in[2];
  const float* b0    = (const float*)d_in[3];
  const float* w_in1 = (const float*)d_in[4];
  const float* w_hh1 = (const float*)d_in[5];
  const float* b1    = (const float*)d_in[6];
  const float* rdo   = (const float*)d_in[7];
  float* out = (float*)d_out;
  float* wsf = (float*)d_ws;

  dim3 tb(32, 8);
  transpose_k<<<dim3(32, 32), tb, 0, stream>>>(w_hh0, wsf + OFF_WT_HH0, 1024, 1024);
  transpose_k<<<dim3(32, 32), tb, 0, stream>>>(w_in1, wsf + OFF_WT_IN1, 1024, 1024);
  transpose_k<<<dim3(32, 32), tb, 0, stream>>>(w_hh1, wsf + OFF_WT_HH1, 1024, 1024);
  transpose_k<<<dim3(32, 2),  tb, 0, stream>>>(w_in0, wsf + OFF_WT_IN0, 64, 1024);
  transpose_k<<<dim3(2, 64),  tb, 0, stream>>>(rdo,   wsf + OFF_RT, 2048, 64);

  // zero the state slots read before first writes (r=0 reads s0g[1]; r=1 reads s1g[0])
  (void)hipMemsetAsync(wsf + OFF_S0G + NBR, 0, NBR * sizeof(float), stream);
  (void)hipMemsetAsync(wsf + OFF_S1G, 0, NBR * sizeof(float), stream);
  (void)hipMemsetAsync(wsf + OFF_FLAGS, 0, 4 * 64 * sizeof(unsigned), stream);

  // 40KB dynamic LDS pad -> 88KB/block -> 1 block/CU; 16 waves -> 4/SIMD (TLP)
  esn_scan_kernel<<<dim3(256), dim3(1024), 40960, stream>>>(x, b0, b1, wsf, out);
}

// Round 15
// 11478.811 us; speedup vs baseline: 1.5843x; 1.5843x over previous
//
#include <hip/hip_runtime.h>
#include <math.h>

#define ESN_B 16
#define ESN_T 2048
#define ESN_R 1024
#define ESN_IN 64
#define NBR (ESN_B * ESN_R)

// ---- workspace layout (float offsets) ----
#define OFF_WT_HH0 0                               // [1024][1024]  W_hh0^T
#define OFF_WT_IN1 (1024 * 1024)                   // [1024][1024]  W_in1^T
#define OFF_WT_HH1 (2 * 1024 * 1024)               // [1024][1024]  W_hh1^T
#define OFF_WT_IN0 (3 * 1024 * 1024)               // [1024][64]    W_in0^T
#define OFF_RT     (OFF_WT_IN0 + 1024 * 64)        // [64][2048]    readout^T
#define OFF_S0G    (OFF_RT + 64 * 2048)            // [2][16][1024] s0 double buffer
#define OFF_S1G    (OFF_S0G + 2 * NBR)             // [2][16][1024] s1 double buffer
#define OFF_FLAGS  (OFF_S1G + 2 * NBR)             // [4][64] u32 per-block flags

typedef float vfloat4 __attribute__((__vector_size__(16)));

// ---------------- transpose: dst[c][r] = src[r][c] ----------------
__global__ void __launch_bounds__(256) transpose_k(const float* __restrict__ src,
                                                   float* __restrict__ dst,
                                                   int rows, int cols) {
  __shared__ float tile[32][33];
  int bx = blockIdx.x * 32, by = blockIdx.y * 32;
  int tx = threadIdx.x, ty = threadIdx.y;  // 32 x 8
  #pragma unroll
  for (int i = ty; i < 32; i += 8) {
    int r = by + i, c = bx + tx;
    if (r < rows && c < cols) tile[i][tx] = src[(size_t)r * cols + c];
  }
  __syncthreads();
  #pragma unroll
  for (int i = ty; i < 32; i += 8) {
    int c = bx + i, r = by + tx;
    if (c < cols && r < rows) dst[(size_t)c * rows + r] = tile[tx][i];
  }
}

// ---------------- helpers ----------------
__device__ __forceinline__ float fast_tanh(float v) {
  float a = fabsf(v);
  float e = __expf(-2.0f * a);
  float t = __fdividef(1.0f - e, 1.0f + e);
  return copysignf(t, v);
}

__device__ __forceinline__ float dot4(float4 a, float4 b, float acc) {
  acc = fmaf(a.x, b.x, acc);
  acc = fmaf(a.y, b.y, acc);
  acc = fmaf(a.z, b.z, acc);
  acc = fmaf(a.w, b.w, acc);
  return acc;
}

__device__ __forceinline__ float wave_red64(float v) {
  #pragma unroll
  for (int off = 32; off > 0; off >>= 1) v += __shfl_xor(v, off, 64);
  return v;
}

// 4 independent 64-lane sums with 7 shuffles; lane l returns sum a_{l&3}
// (each output is a pure sum of ONE input across lanes — no cross-mixing)
__device__ __forceinline__ float reduce4(float a0, float a1, float a2, float a3,
                                         bool lb0, bool lb1) {
  float uA = lb0 ? a0 : a1, kA = lb0 ? a1 : a0;
  float A = kA + __shfl_xor(uA, 1, 64);
  float uB = lb0 ? a2 : a3, kB = lb0 ? a3 : a2;
  float B = kB + __shfl_xor(uB, 1, 64);
  float uC = lb1 ? A : B, kC = lb1 ? B : A;
  float C = kC + __shfl_xor(uC, 2, 64);
  C += __shfl_xor(C, 4, 64);
  C += __shfl_xor(C, 8, 64);
  C += __shfl_xor(C, 16, 64);
  C += __shfl_xor(C, 32, 64);
  return C;
}

// device-scope (LLC-coherent) memory ops: bypass L1/L2, no cache invalidates
__device__ __forceinline__ void llc_store_f32x4(float* p, float4 v) {
  vfloat4 vv = {v.x, v.y, v.z, v.w};
  asm volatile("global_store_dwordx4 %0, %1, off sc1" :: "v"(p), "v"(vv) : "memory");
}
__device__ __forceinline__ void llc_store_u32(unsigned* p, unsigned v) {
  asm volatile("global_store_dword %0, %1, off sc1" :: "v"(p), "v"(v) : "memory");
}
__device__ __forceinline__ unsigned llc_load_u32(const unsigned* p) {
  unsigned f;
  asm volatile("global_load_dword %0, %1, off sc1\n\ts_waitcnt vmcnt(0)"
               : "=v"(f) : "v"(p) : "memory");
  return f;
}
__device__ __forceinline__ void vmcnt0() {
  asm volatile("s_waitcnt vmcnt(0)" ::: "memory");
}
// raw barriers: do NOT drain vmcnt (unlike __syncthreads)
__device__ __forceinline__ void barrier_only() {
  asm volatile("" ::: "memory");
  __builtin_amdgcn_s_barrier();
  asm volatile("" ::: "memory");
}
__device__ __forceinline__ void barrier_lgkm() {
  asm volatile("s_waitcnt lgkmcnt(0)" ::: "memory");
  __builtin_amdgcn_s_barrier();
  asm volatile("" ::: "memory");
}

// ---------------- persistent fused scan (merged L0+L1 phase) ----------------
// r13 protocol (sc1 exchange, per-block flags, unroll-x2 compile-time slot),
// but ONE compute phase per round: L0(r) and L1(r-1) are independent given
// staged data, so both layers' dots share h-fragments and fold into a single
// reduce4 per batch (lane&3: 0,1 = L0 cols; 2,3 = L1 cols). 3 barriers/round.
// 4 groups x 64 blocks x 512 threads (8 waves, 88KB LDS -> 1 block/CU).
__global__ void __launch_bounds__(512, 2) esn_scan_kernel(
    const float* __restrict__ x,
    const float* __restrict__ b0,
    const float* __restrict__ b1,
    float* __restrict__ wsf,
    float* __restrict__ out) {
  __shared__ float s0l[2][4][1024];  // s0 LDS ring: slot r&1 = s0(r-1)
  __shared__ float s1l[4][1024];     // s1(r-2)
  __shared__ __align__(16) float res[2][4][16];  // [layer][batch][16 cols]
  extern __shared__ float dyn_pad[]; // 40KB occupancy limiter (never touched)
  if (blockIdx.x == 0x7fffffffu) dyn_pad[0] = 1.0f;  // defeat DCE, never runs

  const float* wtHH0 = wsf + OFF_WT_HH0;
  const float* wtIN1 = wsf + OFF_WT_IN1;
  const float* wtHH1 = wsf + OFF_WT_HH1;
  const float* wtIN0 = wsf + OFF_WT_IN0;
  const float* rt    = wsf + OFF_RT;
  float* s0g = wsf + OFF_S0G;
  float* s1g = wsf + OFF_S1G;
  unsigned* flags = (unsigned*)(wsf + OFF_FLAGS);

  const int tid = threadIdx.x;
  const int l = tid & 63;
  const int w = tid >> 6;            // wave 0..7
  const int bid = blockIdx.x;
  const int g = bid >> 6;            // group 0..3
  const int bg = bid & 63;           // block in group
  const int batch0 = g * 4;
  const int wg = bg * 8 + w;         // wave idx in group 0..511
  const int c0 = wg * 2;             // wave's first column (= bg*16 + w*2)
  const int wl2 = w * 2;             // block-local col base
  const bool doRO = (w >= 4);        // waves 4..7: readout (rbl=w-4, roc=bg)
  const int rbl = w - 4;             // readout local batch (RO waves)
  const int rb = batch0 + rbl;       // readout batch
  const int roc = bg;                // readout out-col
  unsigned* gflags = flags + g * 64; // [64 blocks]
  const bool lb0 = (l & 1) != 0;
  const bool lb1 = (l & 2) != 0;

  // ---- persistent per-lane weights as NAMED float4s (k = q*256 + l*4 + j) ----
  float4 wA0_0, wA0_1, wA0_2, wA0_3, wA1_0, wA1_1, wA1_2, wA1_3;
  float4 wB0_0, wB0_1, wB0_2, wB0_3, wB1_0, wB1_1, wB1_2, wB1_3;
  float4 wC0_0, wC0_1, wC0_2, wC0_3, wC1_0, wC1_1, wC1_2, wC1_3;
  float4 rd0, rd1, rd2, rd3, rd4, rd5, rd6, rd7;

#define LOADW(cc) { \
    const float* pA = wtHH0 + (size_t)(c0 + cc) * ESN_R + l * 4; \
    const float* pB = wtIN1 + (size_t)(c0 + cc) * ESN_R + l * 4; \
    const float* pC = wtHH1 + (size_t)(c0 + cc) * ESN_R + l * 4; \
    wA##cc##_0 = *(const float4*)(pA);       wA##cc##_1 = *(const float4*)(pA + 256); \
    wA##cc##_2 = *(const float4*)(pA + 512); wA##cc##_3 = *(const float4*)(pA + 768); \
    wB##cc##_0 = *(const float4*)(pB);       wB##cc##_1 = *(const float4*)(pB + 256); \
    wB##cc##_2 = *(const float4*)(pB + 512); wB##cc##_3 = *(const float4*)(pB + 768); \
    wC##cc##_0 = *(const float4*)(pC);       wC##cc##_1 = *(const float4*)(pC + 256); \
    wC##cc##_2 = *(const float4*)(pC + 512); wC##cc##_3 = *(const float4*)(pC + 768); \
  }
  LOADW(0) LOADW(1)
#undef LOADW

  rd0 = rd1 = rd2 = rd3 = rd4 = rd5 = rd6 = rd7 = make_float4(0.f, 0.f, 0.f, 0.f);
  if (doRO) {
    const float* pr = rt + (size_t)roc * 2048 + l * 4;
    rd0 = *(const float4*)(pr);        rd1 = *(const float4*)(pr + 256);
    rd2 = *(const float4*)(pr + 512);  rd3 = *(const float4*)(pr + 768);
    rd4 = *(const float4*)(pr + 1024); rd5 = *(const float4*)(pr + 1280);
    rd6 = *(const float4*)(pr + 1536); rd7 = *(const float4*)(pr + 1792);
  }
  const float wI0 = wtIN0[(size_t)(c0 + 0) * ESN_IN + l];
  const float wI1 = wtIN0[(size_t)(c0 + 1) * ESN_IN + l];
  // per-lane merged-update bias: lanes 0,1 -> b0[c0+(l&1)]; lanes 2,3 -> b1[c0+(l&1)]
  float bsel = 0.f;
  if (l < 4) bsel = ((l < 2) ? b0 : b1)[c0 + (l & 1)];

  // ---- hoisted pointers (slot-specific, selected at compile time below) ----
  const float* sA0 = s0g + 0 * NBR + batch0 * ESN_R + tid * 4;  // s0 slot0
  const float* sA1 = s0g + 1 * NBR + batch0 * ESN_R + tid * 4;  // s0 slot1
  const float* sB0 = s1g + 0 * NBR + batch0 * ESN_R + tid * 4;
  const float* sB1 = s1g + 1 * NBR + batch0 * ESN_R + tid * 4;
  // wave0 gather-store: lanes 0-15 -> s0g, lanes 16-31 -> s1g
  float* gb = ((l < 16) ? s0g : s1g) +
              (batch0 + ((l >> 2) & 3)) * ESN_R + bg * 16 + (l & 3) * 4;
  float* gbA = gb;            // slot 0
  float* gbB = gb + NBR;      // slot 1
  const float* xbase = x + (size_t)batch0 * ESN_T * ESN_IN + l;

  // One round with compile-time SLOTC (0 or 1). oslot = 1-SLOTC.
#define ESN_ROUND(SLOTC, rr)                                                   \
  {                                                                            \
    const bool doL0 = ((rr) < ESN_T);                                          \
    const bool doL1 = ((rr) >= 1 && (rr) <= ESN_T);                            \
    float xv0 = 0.f, xv1 = 0.f, xv2 = 0.f, xv3 = 0.f;                          \
    if (doL0) {                                                                \
      const float* xp = xbase + (size_t)(rr) * ESN_IN;                         \
      xv0 = xp[0 * ESN_T * ESN_IN];                                            \
      xv1 = xp[1 * ESN_T * ESN_IN];                                            \
      xv2 = xp[2 * ESN_T * ESN_IN];                                            \
      xv3 = xp[3 * ESN_T * ESN_IN];                                            \
    }                                                                          \
    if ((rr) > 0) {                                                            \
      if (w == 0) {                                                            \
        while (!__all(llc_load_u32(&gflags[l]) >= (unsigned)(rr))) {}          \
      }                                                                        \
      barrier_only(); /* syncA: LDS reuse vs prev round's readers */           \
    }                                                                          \
    const float* p0 = SLOTC ? sA0 : sA1; /* stage reads oslot buffers */       \
    const float* p1 = SLOTC ? sB0 : sB1;                                       \
    float4 t0, t1, u0, u1;                                                     \
    asm volatile(                                                              \
        "global_load_dwordx4 %0, %4, off sc1\n\t"                              \
        "global_load_dwordx4 %1, %5, off sc1\n\t"                              \
        "global_load_dwordx4 %2, %6, off sc1\n\t"                              \
        "global_load_dwordx4 %3, %7, off sc1\n\t"                              \
        "s_waitcnt vmcnt(0)"                                                   \
        : "=&v"(t0), "=&v"(t1), "=&v"(u0), "=&v"(u1)                           \
        : "v"(p0), "v"(p0 + 2048), "v"(p1), "v"(p1 + 2048)                     \
        : "memory");                                                           \
    {                                                                          \
      float* d0 = &s0l[SLOTC][0][0] + tid * 4;                                 \
      float* d1 = &s1l[0][0] + tid * 4;                                        \
      *(float4*)(d0)        = t0;                                              \
      *(float4*)(d0 + 2048) = t1;                                              \
      *(float4*)(d1)        = u0;                                              \
      *(float4*)(d1 + 2048) = u1;                                              \
    }                                                                          \
    barrier_lgkm(); /* syncB: s0l + s1l ready */                               \
    _Pragma("unroll")                                                          \
    for (int bb = 0; bb < 4; ++bb) {                                           \
      const float* hp = &s0l[SLOTC][bb][l * 4];                                \
      float4 h0x = *(const float4*)(hp);                                       \
      float4 h1x = *(const float4*)(hp + 256);                                 \
      float4 h2x = *(const float4*)(hp + 512);                                 \
      float4 h3x = *(const float4*)(hp + 768);                                 \
      const float* gp = &s1l[bb][l * 4];                                       \
      float4 g0x = *(const float4*)(gp);                                       \
      float4 g1x = *(const float4*)(gp + 256);                                 \
      float4 g2x = *(const float4*)(gp + 512);                                 \
      float4 g3x = *(const float4*)(gp + 768);                                 \
      float xb = (bb == 0) ? xv0 : (bb == 1) ? xv1 : (bb == 2) ? xv2 : xv3;    \
      float a0 = xb * wI0, a1 = xb * wI1;                                      \
      a0 = dot4(wA0_0, h0x, a0); a0 = dot4(wA0_1, h1x, a0);                    \
      a0 = dot4(wA0_2, h2x, a0); a0 = dot4(wA0_3, h3x, a0);                    \
      a1 = dot4(wA1_0, h0x, a1); a1 = dot4(wA1_1, h1x, a1);                    \
      a1 = dot4(wA1_2, h2x, a1); a1 = dot4(wA1_3, h3x, a1);                    \
      float a2 = 0.f, a3 = 0.f;                                                \
      a2 = dot4(wB0_0, h0x, a2); a2 = dot4(wB0_1, h1x, a2);                    \
      a2 = dot4(wB0_2, h2x, a2); a2 = dot4(wB0_3, h3x, a2);                    \
      a2 = dot4(wC0_0, g0x, a2); a2 = dot4(wC0_1, g1x, a2);                    \
      a2 = dot4(wC0_2, g2x, a2); a2 = dot4(wC0_3, g3x, a2);                    \
      a3 = dot4(wB1_0, h0x, a3); a3 = dot4(wB1_1, h1x, a3);                    \
      a3 = dot4(wB1_2, h2x, a3); a3 = dot4(wB1_3, h3x, a3);                    \
      a3 = dot4(wC1_0, g0x, a3); a3 = dot4(wC1_1, g1x, a3);                    \
      a3 = dot4(wC1_2, g2x, a3); a3 = dot4(wC1_3, g3x, a3);                    \
      float C = reduce4(a0, a1, a2, a3, lb0, lb1);                             \
      if (l < 4) { /* lanes 0,1: L0 cols; lanes 2,3: L1 cols */                \
        const float* pbase = (l < 2) ? &s0l[SLOTC][bb][0] : &s1l[bb][0];       \
        float prev = pbase[c0 + (l & 1)];                                      \
        float nv = 0.5f * prev + 0.5f * fast_tanh(C + bsel);                   \
        bool wr = (l < 2) ? doL0 : doL1;                                       \
        if (wr) res[l >> 1][bb][wl2 + (l & 1)] = nv;                           \
      }                                                                        \
    }                                                                          \
    barrier_lgkm(); /* syncD: res ready */                                     \
    if (w == 0) {                                                              \
      if (l < 32 && ((l < 16) ? doL0 : doL1)) {                                \
        float4 v = *(const float4*)&res[l >> 4][(l >> 2) & 3][(l & 3) * 4];    \
        llc_store_f32x4(SLOTC ? gbB : gbA, v);                                 \
      }                                                                        \
      vmcnt0();                                                                \
      if (l == 0) llc_store_u32(&gflags[bg], (unsigned)((rr) + 1));            \
    }                                                                          \
    if ((rr) >= 2 && doRO) {                                                   \
      const float* sp = &s0l[1 - SLOTC][rbl][l * 4];                           \
      const float* tp = &s1l[rbl][l * 4];                                      \
      float a = 0.f;                                                           \
      a = dot4(rd0, *(const float4*)(sp), a);                                  \
      a = dot4(rd1, *(const float4*)(sp + 256), a);                            \
      a = dot4(rd2, *(const float4*)(sp + 512), a);                            \
      a = dot4(rd3, *(const float4*)(sp + 768), a);                            \
      a = dot4(rd4, *(const float4*)(tp), a);                                  \
      a = dot4(rd5, *(const float4*)(tp + 256), a);                            \
      a = dot4(rd6, *(const float4*)(tp + 512), a);                            \
      a = dot4(rd7, *(const float4*)(tp + 768), a);                            \
      a = wave_red64(a);                                                       \
      if (l == 0) out[((size_t)rb * ESN_T + ((rr) - 2)) * ESN_IN + roc] = a;   \
    }                                                                          \
  }

  // 2050 rounds = 1025 unrolled pairs; slot alternates 0,1 at compile time
  for (int rp = 0; rp < (ESN_T + 2) / 2; ++rp) {
    const int r0 = rp * 2;
    ESN_ROUND(0, r0)
    ESN_ROUND(1, r0 + 1)
  }
#undef ESN_ROUND
}

// ---------------- host launch ----------------
extern "C" void kernel_launch(void* const* d_in, const int* in_sizes, int n_in,
                              void* d_out, int out_size, void* d_ws, size_t ws_size,
                              hipStream_t stream) {
  (void)in_sizes; (void)n_in; (void)out_size; (void)ws_size;
  const float* x     = (const float*)d_in[0];
  const float* w_in0 = (const float*)d_in[1];
  const float* w_hh0 = (const float*)d_in[2];
  const float* b0    = (const float*)d_in[3];
  const float* w_in1 = (const float*)d_in[4];
  const float* w_hh1 = (const float*)d_in[5];
  const float* b1    = (const float*)d_in[6];
  const float* rdo   = (const float*)d_in[7];
  float* out = (float*)d_out;
  float* wsf = (float*)d_ws;

  dim3 tb(32, 8);
  transpose_k<<<dim3(32, 32), tb, 0, stream>>>(w_hh0, wsf + OFF_WT_HH0, 1024, 1024);
  transpose_k<<<dim3(32, 32), tb, 0, stream>>>(w_in1, wsf + OFF_WT_IN1, 1024, 1024);
  transpose_k<<<dim3(32, 32), tb, 0, stream>>>(w_hh1, wsf + OFF_WT_HH1, 1024, 1024);
  transpose_k<<<dim3(32, 2),  tb, 0, stream>>>(w_in0, wsf + OFF_WT_IN0, 64, 1024);
  transpose_k<<<dim3(2, 64),  tb, 0, stream>>>(rdo,   wsf + OFF_RT, 2048, 64);

  // zero the state slots read before first writes (r=0 reads s0g[1], s1g[1]
  // — s1g[1] is read as dot-fodder before first write, zero both s1 slots)
  (void)hipMemsetAsync(wsf + OFF_S0G + NBR, 0, NBR * sizeof(float), stream);
  (void)hipMemsetAsync(wsf + OFF_S1G, 0, 2 * NBR * sizeof(float), stream);
  (void)hipMemsetAsync(wsf + OFF_FLAGS, 0, 4 * 64 * sizeof(unsigned), stream);

  // 40KB dynamic LDS pad -> 88KB/block -> 1 block/CU; 8 waves -> 2/SIMD (TLP)
  esn_scan_kernel<<<dim3(256), dim3(512), 40960, stream>>>(x, b0, b1, wsf, out);
}